// Round 4
// baseline (171.483 us; speedup 1.0000x reference)
//
#include <hip/hip_runtime.h>
#include <hip/hip_bf16.h>
#include <math.h>

#define B_ 4
#define N_ 512
#define D_ 128
#define O_ 64
#define H_ 4

#define SELU_SCALE 1.0507009873554805f
#define SELU_SCALE_ALPHA 1.7580993408473766f  // scale * alpha

typedef short  short8 __attribute__((ext_vector_type(8)));
typedef float  f32x4  __attribute__((ext_vector_type(4)));

__device__ __forceinline__ ushort bf16rne(float f) {
    uint u = __float_as_uint(f);
    return (ushort)((u + 0x7fffu + ((u >> 16) & 1u)) >> 16);
}
__device__ __forceinline__ void bf16split(float f, ushort& h, ushort& l) {
    h = bf16rne(f);
    float hf = __uint_as_float(((uint)h) << 16);
    l = bf16rne(f - hf);
}

// ---------------------------------------------------------------------------
// prep_frags (validated r3): four fragment tensors by blockIdx range.
//  A (blk 0..127):   xf  — x frags, K=d orient. fi=(b*32+jf)*8 + kc*2 + s
//  B (blk 128..255): xfT — x frags, K=j orient. fi=((b*16+kc)*8+d0)*2+s
//  C (blk 256..271): pwf — PW' frags (kappa=(h,d) reindex). fi=(kc*4+o0)*2+s
//  D (blk 272..275): nwf — NW frags. fi=(kc*4+o0)*2+s
// ---------------------------------------------------------------------------
__global__ __launch_bounds__(256) void prep_frags(
    const float* __restrict__ x, const float* __restrict__ PW,
    const float* __restrict__ NW,
    ushort* __restrict__ xf, ushort* __restrict__ xfT,
    ushort* __restrict__ pwf, ushort* __restrict__ nwf)
{
    const int bid = blockIdx.x;
    const int tid = threadIdx.x;

    if (bid < 128) {
        const int t  = bid * 256 + tid;
        const int jg = t >> 4;
        const int dc = t & 15;
        const int jf = jg >> 4;
        const int kc = dc >> 2, q = dc & 3;
        const int lane = (jg & 15) | (q << 4);

        const f32x4 v0 = *(const f32x4*)&x[t * 8];
        const f32x4 v1 = *(const f32x4*)&x[t * 8 + 4];
        float vv[8] = {v0[0], v0[1], v0[2], v0[3], v1[0], v1[1], v1[2], v1[3]};
        short8 h8, l8;
        #pragma unroll
        for (int e = 0; e < 8; ++e) {
            ushort h, l; bf16split(vv[e], h, l);
            h8[e] = (short)h; l8[e] = (short)l;
        }
        const int fi = (jf * 4 + kc) * 2;
        *(short8*)&xf[(size_t)fi * 512 + lane * 8]       = h8;
        *(short8*)&xf[(size_t)(fi + 1) * 512 + lane * 8] = l8;
    } else if (bid < 256) {
        const int t    = (bid - 128) * 256 + tid;
        const int lane = t & 63, fr = t >> 6;
        const int d0 = fr & 7, kc = (fr >> 3) & 15, b = fr >> 7;
        const int l15 = lane & 15, q4 = lane >> 4;
        short8 h8, l8;
        #pragma unroll
        for (int e = 0; e < 8; ++e) {
            const float v = x[(size_t)((b * 512) + kc * 32 + q4 * 8 + e) * 128 + d0 * 16 + l15];
            ushort h, l; bf16split(v, h, l);
            h8[e] = (short)h; l8[e] = (short)l;
        }
        *(short8*)&xfT[(size_t)(fr * 2) * 512 + lane * 8]     = h8;
        *(short8*)&xfT[(size_t)(fr * 2 + 1) * 512 + lane * 8] = l8;
    } else if (bid < 272) {
        const int t    = (bid - 256) * 256 + tid;
        const int lane = t & 63, fr = t >> 6;
        const int o0 = fr & 3, kc = fr >> 2;
        const int l15 = lane & 15, q4 = lane >> 4;
        short8 h8, l8;
        #pragma unroll
        for (int e = 0; e < 8; ++e) {
            const int kk = kc * 32 + q4 * 8 + e;
            const int d = kk & 127, h = kk >> 7;
            const float v = PW[(d * 4 + h) * O_ + o0 * 16 + l15];
            ushort hh, ll; bf16split(v, hh, ll);
            h8[e] = (short)hh; l8[e] = (short)ll;
        }
        *(short8*)&pwf[(size_t)(fr * 2) * 512 + lane * 8]     = h8;
        *(short8*)&pwf[(size_t)(fr * 2 + 1) * 512 + lane * 8] = l8;
    } else {
        const int t    = (bid - 272) * 256 + tid;
        const int lane = t & 63, fr = t >> 6;
        const int o0 = fr & 3, kc = fr >> 2;
        const int l15 = lane & 15, q4 = lane >> 4;
        short8 h8, l8;
        #pragma unroll
        for (int e = 0; e < 8; ++e) {
            const float v = NW[(kc * 32 + q4 * 8 + e) * O_ + o0 * 16 + l15];
            ushort hh, ll; bf16split(v, hh, ll);
            h8[e] = (short)hh; l8[e] = (short)ll;
        }
        *(short8*)&nwf[(size_t)(fr * 2) * 512 + lane * 8]     = h8;
        *(short8*)&nwf[(size_t)(fr * 2 + 1) * 512 + lane * 8] = l8;
    }
}

// ---------------------------------------------------------------------------
// attn_scores: per-(b,i). o-SPLIT across waves: wave w owns o = w*16..+15.
// A-frags (G^T rows) built in registers from global Wa; x tiles (16 j) staged
// through a 16KB LDS double buffer; am partials combined via LDS float atomics;
// aggregation x1 = P.X via MFMA (xfT). Writes X1h/X1l bf16 pair.
// ---------------------------------------------------------------------------
__global__ __launch_bounds__(256, 3) void attn_scores(
    const float* __restrict__ x,
    const ushort* __restrict__ xf,
    const ushort* __restrict__ xfT,
    const float* __restrict__ Wa,
    const float* __restrict__ ba,
    const float* __restrict__ AW,
    ushort* __restrict__ X1h, ushort* __restrict__ X1l)
{
    __shared__ ushort sB[2][8][512];   // 16KB staging; reused as float sXp[2048] in phase 3
    __shared__ float  sP[4 * 512];     // logits (ds_add accumulated) -> probs

    const int tid  = threadIdx.x;
    const int i    = blockIdx.x;
    const int bB   = blockIdx.y;
    const int lane = tid & 63;
    const int w    = tid >> 6;
    const int l15  = lane & 15;
    const int q4   = lane >> 4;

    // zero logit accumulator (8KB)
    *(f32x4*)&sP[tid * 4]        = (f32x4){0.f, 0.f, 0.f, 0.f};
    *(f32x4*)&sP[1024 + tid * 4] = (f32x4){0.f, 0.f, 0.f, 0.f};

    // ---- A-frags: G^T[o][d] = xi[d]*Wa[d][o], rows o = w*16+l15, in regs ----
    const float* xi = x + ((size_t)bB * N_ + i) * D_;
    const int oa = w * 16 + l15;
    short8 gh[4], gl[4];
    #pragma unroll
    for (int kc = 0; kc < 4; ++kc) {
        const int d0 = kc * 32 + q4 * 8;
        const f32x4 x0 = *(const f32x4*)&xi[d0];
        const f32x4 x1 = *(const f32x4*)&xi[d0 + 4];
        #pragma unroll
        for (int e = 0; e < 8; ++e) {
            const float xe = (e < 4) ? x0[e & 3] : x1[e & 3];
            const float g = xe * Wa[(d0 + e) * O_ + oa];
            ushort h, l; bf16split(g, h, l);
            gh[kc][e] = (short)h; gl[kc][e] = (short)l;
        }
    }

    // ---- hoisted epilogue constants (ji-invariant) ----
    const int oc = w * 16 + q4 * 4;                  // C-row base o for this lane
    const f32x4 aw0 = *(const f32x4*)&AW[(oc + 0) * H_];
    const f32x4 aw1 = *(const f32x4*)&AW[(oc + 1) * H_];
    const f32x4 aw2 = *(const f32x4*)&AW[(oc + 2) * H_];
    const f32x4 aw3 = *(const f32x4*)&AW[(oc + 3) * H_];
    const f32x4 b2 = { 2.f * ba[oc], 2.f * ba[oc + 1], 2.f * ba[oc + 2], 2.f * ba[oc + 3] };

    // ---- phase 1: per-16j tiles; reg-staged LDS dbuf; 1 barrier per tile ----
    const ushort* xfb = xf + (size_t)(bB * 32) * 8 * 512;
    short8 R0 = *(const short8*)&xfb[(size_t)(0 * 8 + 2 * w) * 512 + lane * 8];
    short8 R1 = *(const short8*)&xfb[(size_t)(0 * 8 + 2 * w + 1) * 512 + lane * 8];
    *(short8*)&sB[0][2 * w][lane * 8]     = R0;
    *(short8*)&sB[0][2 * w + 1][lane * 8] = R1;
    R0 = *(const short8*)&xfb[(size_t)(1 * 8 + 2 * w) * 512 + lane * 8];
    R1 = *(const short8*)&xfb[(size_t)(1 * 8 + 2 * w + 1) * 512 + lane * 8];
    __syncthreads();

    for (int jf = 0; jf < 32; ++jf) {
        const int n = jf & 1;
        if (jf < 31) {                     // write tile jf+1 (loaded >=1 iter ago)
            *(short8*)&sB[n ^ 1][2 * w][lane * 8]     = R0;
            *(short8*)&sB[n ^ 1][2 * w + 1][lane * 8] = R1;
        }
        if (jf < 30) {                     // issue loads for tile jf+2
            R0 = *(const short8*)&xfb[(size_t)((jf + 2) * 8 + 2 * w) * 512 + lane * 8];
            R1 = *(const short8*)&xfb[(size_t)((jf + 2) * 8 + 2 * w + 1) * 512 + lane * 8];
        }

        f32x4 acc = {0.f, 0.f, 0.f, 0.f};
        #pragma unroll
        for (int kc = 0; kc < 4; ++kc) {
            const short8 bh = *(const short8*)&sB[n][kc * 2][lane * 8];
            const short8 bl = *(const short8*)&sB[n][kc * 2 + 1][lane * 8];
            acc = __builtin_amdgcn_mfma_f32_16x16x32_bf16(gh[kc], bh, acc, 0, 0, 0);
            acc = __builtin_amdgcn_mfma_f32_16x16x32_bf16(gl[kc], bh, acc, 0, 0, 0);
            acc = __builtin_amdgcn_mfma_f32_16x16x32_bf16(gh[kc], bl, acc, 0, 0, 0);
        }

        // epilogue: tanh + am over this lane's 4 o's (AW in regs)
        f32x4 am;
        {
            const float e0 = __expf(fmaf(acc[0], 2.f, b2[0]));
            const float a0 = fmaf(-2.f, __builtin_amdgcn_rcpf(e0 + 1.f), 1.f);
            am = a0 * aw0;
            const float e1 = __expf(fmaf(acc[1], 2.f, b2[1]));
            const float a1 = fmaf(-2.f, __builtin_amdgcn_rcpf(e1 + 1.f), 1.f);
            am += a1 * aw1;
            const float e2 = __expf(fmaf(acc[2], 2.f, b2[2]));
            const float a2 = fmaf(-2.f, __builtin_amdgcn_rcpf(e2 + 1.f), 1.f);
            am += a2 * aw2;
            const float e3 = __expf(fmaf(acc[3], 2.f, b2[3]));
            const float a3 = fmaf(-2.f, __builtin_amdgcn_rcpf(e3 + 1.f), 1.f);
            am += a3 * aw3;
        }
        #pragma unroll
        for (int k = 0; k < 4; ++k) {      // reduce over q4 groups (16 o of this wave)
            am[k] += __shfl_xor(am[k], 16);
            am[k] += __shfl_xor(am[k], 32);
        }
        const float amsel = (q4 == 0) ? am[0] : (q4 == 1) ? am[1] : (q4 == 2) ? am[2] : am[3];
        atomicAdd(&sP[q4 * 512 + jf * 16 + l15], amsel);   // combine 4 wave o-slices
        __syncthreads();
    }

    // ---- phase 2: softmax over j, one wave per head ----
    {
        const int h = w;
        float v[8];
        float m = -INFINITY;
        #pragma unroll
        for (int k = 0; k < 8; ++k) {
            v[k] = sP[h * N_ + k * 64 + lane];
            m = fmaxf(m, v[k]);
        }
        #pragma unroll
        for (int s = 32; s >= 1; s >>= 1) m = fmaxf(m, __shfl_xor(m, s));
        float l = 0.f;
        #pragma unroll
        for (int k = 0; k < 8; ++k) { v[k] = __expf(v[k] - m); l += v[k]; }
        #pragma unroll
        for (int s = 32; s >= 1; s >>= 1) l += __shfl_xor(l, s);
        const float rinv = 1.f / l;
        #pragma unroll
        for (int k = 0; k < 8; ++k) sP[h * N_ + k * 64 + lane] = v[k] * rinv;
    }
    __syncthreads();

    // ---- phase 3: x1 = P.X via MFMA (A = P rows h, B = xfT K=j) ----
    f32x4 acc2[8];
    {
        const f32x4 z = {0.f, 0.f, 0.f, 0.f};
        #pragma unroll
        for (int nf = 0; nf < 8; ++nf) acc2[nf] = z;
    }
    #pragma unroll
    for (int c = 0; c < 4; ++c) {
        const int kc = w * 4 + c;
        const f32x4 p0 = *(const f32x4*)&sP[(l15 & 3) * 512 + kc * 32 + q4 * 8];
        const f32x4 p1 = *(const f32x4*)&sP[(l15 & 3) * 512 + kc * 32 + q4 * 8 + 4];
        float pv[8] = {p0[0], p0[1], p0[2], p0[3], p1[0], p1[1], p1[2], p1[3]};
        short8 pah, pal;
        #pragma unroll
        for (int e = 0; e < 8; ++e) {
            ushort h, l; bf16split(pv[e], h, l);
            pah[e] = (short)h; pal[e] = (short)l;
        }
        #pragma unroll
        for (int nf = 0; nf < 8; ++nf) {
            const size_t f2 = ((size_t)(bB * 16 + kc) * 8 + nf) * 2;
            const short8 xh = *(const short8*)&xfT[f2 * 512 + lane * 8];
            const short8 xl = *(const short8*)&xfT[(f2 + 1) * 512 + lane * 8];
            acc2[nf] = __builtin_amdgcn_mfma_f32_16x16x32_bf16(pah, xh, acc2[nf], 0, 0, 0);
            acc2[nf] = __builtin_amdgcn_mfma_f32_16x16x32_bf16(pal, xh, acc2[nf], 0, 0, 0);
            acc2[nf] = __builtin_amdgcn_mfma_f32_16x16x32_bf16(pah, xl, acc2[nf], 0, 0, 0);
        }
    }
    float* sXp = (float*)sB;   // reuse staging LDS as [4 waves][4 h][128 d]
    if (q4 == 0) {
        #pragma unroll
        for (int nf = 0; nf < 8; ++nf)
            #pragma unroll
            for (int r = 0; r < 4; ++r)
                sXp[(w * 4 + r) * 128 + nf * 16 + l15] = acc2[nf][r];
    }
    __syncthreads();

    // ---- phase 3b: reduce wave partials, split, store X1 ----
    {
        const int kap = tid * 2;
        const size_t row = (size_t)bB * N_ + i;
        float v0 = 0.f, v1 = 0.f;
        #pragma unroll
        for (int ww = 0; ww < 4; ++ww) {
            v0 += sXp[(ww * 4 + (kap >> 7)) * 128 + (kap & 127)];
            v1 += sXp[(ww * 4 + ((kap + 1) >> 7)) * 128 + ((kap + 1) & 127)];
        }
        ushort h0, l0, h1, l1;
        bf16split(v0, h0, l0);
        bf16split(v1, h1, l1);
        *(uint*)&X1h[row * 512 + kap] = (uint)h0 | ((uint)h1 << 16);
        *(uint*)&X1l[row * 512 + kap] = (uint)l0 | ((uint)l1 << 16);
    }
}

// ---------------------------------------------------------------------------
// proj_y_part: y = x1.PW' + x.NW + biases (MFMA) + per-block BN partial sums.
// ---------------------------------------------------------------------------
__global__ __launch_bounds__(256) void proj_y_part(
    const ushort* __restrict__ X1h, const ushort* __restrict__ X1l,
    const ushort* __restrict__ xf,
    const ushort* __restrict__ pwf, const ushort* __restrict__ nwf,
    const float* __restrict__ PWb, const float* __restrict__ NWb,
    float* __restrict__ y, float* __restrict__ part)
{
    const int tid = threadIdx.x, bid = blockIdx.x;
    const int lane = tid & 63, w = tid >> 6;
    const int l15 = lane & 15, q4 = lane >> 4;
    const int bi0 = bid * 16;
    const int b = bi0 >> 9, ig = (bi0 >> 4) & 31;

    f32x4 acc = {0.f, 0.f, 0.f, 0.f};
    #pragma unroll
    for (int kc = 0; kc < 16; ++kc) {
        const size_t arow = (size_t)(bi0 + l15) * 512 + kc * 32 + q4 * 8;
        const short8 ah = *(const short8*)&X1h[arow];
        const short8 al = *(const short8*)&X1l[arow];
        const int f3 = (kc * 4 + w) * 2;
        const short8 bhv = *(const short8*)&pwf[(size_t)f3 * 512 + lane * 8];
        const short8 blv = *(const short8*)&pwf[(size_t)(f3 + 1) * 512 + lane * 8];
        acc = __builtin_amdgcn_mfma_f32_16x16x32_bf16(ah, bhv, acc, 0, 0, 0);
        acc = __builtin_amdgcn_mfma_f32_16x16x32_bf16(al, bhv, acc, 0, 0, 0);
        acc = __builtin_amdgcn_mfma_f32_16x16x32_bf16(ah, blv, acc, 0, 0, 0);
    }
    #pragma unroll
    for (int kc = 0; kc < 4; ++kc) {
        const size_t fi = ((size_t)(b * 32 + ig) * 4 + kc) * 2;
        const short8 ah = *(const short8*)&xf[fi * 512 + lane * 8];
        const short8 al = *(const short8*)&xf[(fi + 1) * 512 + lane * 8];
        const int f4 = (kc * 4 + w) * 2;
        const short8 bhv = *(const short8*)&nwf[(size_t)f4 * 512 + lane * 8];
        const short8 blv = *(const short8*)&nwf[(size_t)(f4 + 1) * 512 + lane * 8];
        acc = __builtin_amdgcn_mfma_f32_16x16x32_bf16(ah, bhv, acc, 0, 0, 0);
        acc = __builtin_amdgcn_mfma_f32_16x16x32_bf16(al, bhv, acc, 0, 0, 0);
        acc = __builtin_amdgcn_mfma_f32_16x16x32_bf16(ah, blv, acc, 0, 0, 0);
    }
    const int oo = w * 16 + l15;
    const float bias = PWb[oo] + NWb[oo];
    float s = 0.f, sq = 0.f;
    #pragma unroll
    for (int r = 0; r < 4; ++r) {
        const float yv = acc[r] + bias;
        y[(size_t)(bi0 + q4 * 4 + r) * O_ + oo] = yv;
        s += yv; sq += yv * yv;
    }
    s  += __shfl_xor(s, 16);  s  += __shfl_xor(s, 32);
    sq += __shfl_xor(sq, 16); sq += __shfl_xor(sq, 32);
    if (q4 == 0) {
        part[bid * 256 + oo]       = s;
        part[bid * 256 + 128 + oo] = sq;
    }
}

__global__ __launch_bounds__(256) void bn_final(
    const float* __restrict__ part, const float* __restrict__ gamma,
    const float* __restrict__ beta, float* __restrict__ stats)
{
    const int tid = threadIdx.x, o = tid & 63, g = tid >> 6;
    float s = 0.f, sq = 0.f;
    #pragma unroll 4
    for (int k = 0; k < 32; ++k) {
        const int blk = g * 32 + k;
        s  += part[blk * 256 + o];
        sq += part[blk * 256 + 128 + o];
    }
    __shared__ float ls[4][64], lq[4][64];
    ls[g][o] = s; lq[g][o] = sq;
    __syncthreads();
    if (tid < 64) {
        const float inv = 1.f / 2048.f;
        const float ts = ls[0][tid] + ls[1][tid] + ls[2][tid] + ls[3][tid];
        const float tq = lq[0][tid] + lq[1][tid] + lq[2][tid] + lq[3][tid];
        const float mu  = ts * inv;
        const float var = tq * inv - mu * mu;
        const float rstd = rsqrtf(var + 1e-5f);
        const float sc = gamma[tid] * rstd;
        stats[tid]      = sc;
        stats[64 + tid] = beta[tid] - mu * sc;
    }
}

__global__ __launch_bounds__(256) void bn_apply(
    float* __restrict__ y, const float* __restrict__ stats)
{
    const int idx = blockIdx.x * 256 + threadIdx.x;
    f32x4 v = *(f32x4*)&y[idx * 4];
    const int o0 = (idx * 4) & 63;
    #pragma unroll
    for (int k = 0; k < 4; ++k) {
        const float t = v[k] * stats[o0 + k] + stats[64 + o0 + k];
        v[k] = t > 0.f ? SELU_SCALE * t : SELU_SCALE_ALPHA * (__expf(t) - 1.f);
    }
    *(f32x4*)&y[idx * 4] = v;
}

extern "C" void kernel_launch(void* const* d_in, const int* in_sizes, int n_in,
                              void* d_out, int out_size, void* d_ws, size_t ws_size,
                              hipStream_t stream)
{
    (void)in_sizes; (void)n_in; (void)out_size; (void)ws_size;
    const float* x     = (const float*)d_in[0];
    const float* Wa    = (const float*)d_in[1];
    const float* ba    = (const float*)d_in[2];
    const float* AW    = (const float*)d_in[3];
    const float* PW    = (const float*)d_in[4];
    const float* PWb   = (const float*)d_in[5];
    const float* NW    = (const float*)d_in[6];
    const float* NWb   = (const float*)d_in[7];
    const float* gamma = (const float*)d_in[8];
    const float* beta  = (const float*)d_in[9];

    char* ws = (char*)d_ws;
    ushort* xf    = (ushort*)ws;                                   // 1 MB
    ushort* xfT   = (ushort*)(ws + (1 << 20));                     // 1 MB
    ushort* X1h   = (ushort*)(ws + (2 << 20));                     // 2 MB
    ushort* X1l   = (ushort*)(ws + (4 << 20));                     // 2 MB
    ushort* pwf   = (ushort*)(ws + (6 << 20));                     // 128 KB
    ushort* nwf   = (ushort*)(ws + (6 << 20) + (128 << 10));       // 32 KB
    float*  part  = (float*)(ws + (6 << 20) + (160 << 10));        // 128 KB
    float*  stats = (float*)(ws + (6 << 20) + (288 << 10));        // 512 B
    float*  y     = (float*)d_out;

    prep_frags<<<276, 256, 0, stream>>>(x, PW, NW, xf, xfT, pwf, nwf);
    attn_scores<<<dim3(N_, B_), 256, 0, stream>>>(x, xf, xfT, Wa, ba, AW, X1h, X1l);
    proj_y_part<<<128, 256, 0, stream>>>(X1h, X1l, xf, pwf, nwf, PWb, NWb, y, part);
    bn_final<<<1, 256, 0, stream>>>(part, gamma, beta, stats);
    bn_apply<<<128, 256, 0, stream>>>(y, stats);
}

// Round 5
// 124.087 us; speedup vs baseline: 1.3820x; 1.3820x over previous
//
#include <hip/hip_runtime.h>
#include <hip/hip_bf16.h>
#include <math.h>

#define B_ 4
#define N_ 512
#define D_ 128
#define O_ 64
#define H_ 4

#define SELU_SCALE 1.0507009873554805f
#define SELU_SCALE_ALPHA 1.7580993408473766f  // scale * alpha

typedef short  short8 __attribute__((ext_vector_type(8)));
typedef float  f32x4  __attribute__((ext_vector_type(4)));

__device__ __forceinline__ ushort bf16rne(float f) {
    uint u = __float_as_uint(f);
    return (ushort)((u + 0x7fffu + ((u >> 16) & 1u)) >> 16);
}
__device__ __forceinline__ void bf16split(float f, ushort& h, ushort& l) {
    h = bf16rne(f);
    float hf = __uint_as_float(((uint)h) << 16);
    l = bf16rne(f - hf);
}

// ---------------------------------------------------------------------------
// prep_frags (validated r3/r4): four fragment tensors by blockIdx range.
//  A (blk 0..127):   xf  — x frags, K=d orient. fi=(jf_global*4+kc)*2+s
//  B (blk 128..255): xfT — x frags, K=j orient. fi=((b*16+kc)*8+d0)*2+s
//  C (blk 256..271): pwf — PW' frags (kappa=(h,d) reindex). fi=(kc*4+o0)*2+s
//  D (blk 272..275): nwf — NW frags. fi=(kc*4+o0)*2+s
// ---------------------------------------------------------------------------
__global__ __launch_bounds__(256) void prep_frags(
    const float* __restrict__ x, const float* __restrict__ PW,
    const float* __restrict__ NW,
    ushort* __restrict__ xf, ushort* __restrict__ xfT,
    ushort* __restrict__ pwf, ushort* __restrict__ nwf)
{
    const int bid = blockIdx.x;
    const int tid = threadIdx.x;

    if (bid < 128) {
        const int t  = bid * 256 + tid;
        const int jg = t >> 4;
        const int dc = t & 15;
        const int jf = jg >> 4;
        const int kc = dc >> 2, q = dc & 3;
        const int lane = (jg & 15) | (q << 4);

        const f32x4 v0 = *(const f32x4*)&x[t * 8];
        const f32x4 v1 = *(const f32x4*)&x[t * 8 + 4];
        float vv[8] = {v0[0], v0[1], v0[2], v0[3], v1[0], v1[1], v1[2], v1[3]};
        short8 h8, l8;
        #pragma unroll
        for (int e = 0; e < 8; ++e) {
            ushort h, l; bf16split(vv[e], h, l);
            h8[e] = (short)h; l8[e] = (short)l;
        }
        const int fi = (jf * 4 + kc) * 2;
        *(short8*)&xf[(size_t)fi * 512 + lane * 8]       = h8;
        *(short8*)&xf[(size_t)(fi + 1) * 512 + lane * 8] = l8;
    } else if (bid < 256) {
        const int t    = (bid - 128) * 256 + tid;
        const int lane = t & 63, fr = t >> 6;
        const int d0 = fr & 7, kc = (fr >> 3) & 15, b = fr >> 7;
        const int l15 = lane & 15, q4 = lane >> 4;
        short8 h8, l8;
        #pragma unroll
        for (int e = 0; e < 8; ++e) {
            const float v = x[(size_t)((b * 512) + kc * 32 + q4 * 8 + e) * 128 + d0 * 16 + l15];
            ushort h, l; bf16split(v, h, l);
            h8[e] = (short)h; l8[e] = (short)l;
        }
        *(short8*)&xfT[(size_t)(fr * 2) * 512 + lane * 8]     = h8;
        *(short8*)&xfT[(size_t)(fr * 2 + 1) * 512 + lane * 8] = l8;
    } else if (bid < 272) {
        const int t    = (bid - 256) * 256 + tid;
        const int lane = t & 63, fr = t >> 6;
        const int o0 = fr & 3, kc = fr >> 2;
        const int l15 = lane & 15, q4 = lane >> 4;
        short8 h8, l8;
        #pragma unroll
        for (int e = 0; e < 8; ++e) {
            const int kk = kc * 32 + q4 * 8 + e;
            const int d = kk & 127, h = kk >> 7;
            const float v = PW[(d * 4 + h) * O_ + o0 * 16 + l15];
            ushort hh, ll; bf16split(v, hh, ll);
            h8[e] = (short)hh; l8[e] = (short)ll;
        }
        *(short8*)&pwf[(size_t)(fr * 2) * 512 + lane * 8]     = h8;
        *(short8*)&pwf[(size_t)(fr * 2 + 1) * 512 + lane * 8] = l8;
    } else {
        const int t    = (bid - 272) * 256 + tid;
        const int lane = t & 63, fr = t >> 6;
        const int o0 = fr & 3, kc = fr >> 2;
        const int l15 = lane & 15, q4 = lane >> 4;
        short8 h8, l8;
        #pragma unroll
        for (int e = 0; e < 8; ++e) {
            const float v = NW[(kc * 32 + q4 * 8 + e) * O_ + o0 * 16 + l15];
            ushort hh, ll; bf16split(v, hh, ll);
            h8[e] = (short)hh; l8[e] = (short)ll;
        }
        *(short8*)&nwf[(size_t)(fr * 2) * 512 + lane * 8]     = h8;
        *(short8*)&nwf[(size_t)(fr * 2 + 1) * 512 + lane * 8] = l8;
    }
}

// epilogue for one 16-j score tile: tanh + am over this lane's 4 o-rows,
// reduce over the wave's 16 o's, store head-q4 partial to this wave's row.
__device__ __forceinline__ void score_epilogue(
    const f32x4& acc, int jf, int w, int q4, int l15,
    const f32x4& aw0, const f32x4& aw1, const f32x4& aw2, const f32x4& aw3,
    const f32x4& b2, float* __restrict__ sAmpF)
{
    f32x4 am;
    const float e0 = __expf(fmaf(acc[0], 2.f, b2[0]));
    am  = fmaf(-2.f, __builtin_amdgcn_rcpf(e0 + 1.f), 1.f) * aw0;
    const float e1 = __expf(fmaf(acc[1], 2.f, b2[1]));
    am += fmaf(-2.f, __builtin_amdgcn_rcpf(e1 + 1.f), 1.f) * aw1;
    const float e2 = __expf(fmaf(acc[2], 2.f, b2[2]));
    am += fmaf(-2.f, __builtin_amdgcn_rcpf(e2 + 1.f), 1.f) * aw2;
    const float e3 = __expf(fmaf(acc[3], 2.f, b2[3]));
    am += fmaf(-2.f, __builtin_amdgcn_rcpf(e3 + 1.f), 1.f) * aw3;
    #pragma unroll
    for (int k = 0; k < 4; ++k) {
        am[k] += __shfl_xor(am[k], 16);
        am[k] += __shfl_xor(am[k], 32);
    }
    const float amsel = (q4 == 0) ? am[0] : (q4 == 1) ? am[1] : (q4 == 2) ? am[2] : am[3];
    sAmpF[(w * 4 + q4) * 528 + jf * 16 + l15] = amsel;   // private row, no atomic
}

// ---------------------------------------------------------------------------
// attn_scores: per-(b,i). o-split across waves (wave w owns o=w*16..+15).
// Phase 1 is BARRIER-FREE: B-frags stream global->reg (L1-shared across
// waves, static double buffer), am partials go to per-wave LDS rows.
// ---------------------------------------------------------------------------
__global__ __launch_bounds__(256, 3) void attn_scores(
    const float* __restrict__ x,
    const ushort* __restrict__ xf,
    const ushort* __restrict__ xfT,
    const float* __restrict__ Wa,
    const float* __restrict__ ba,
    const float* __restrict__ AW,
    ushort* __restrict__ X1h, ushort* __restrict__ X1l)
{
    __shared__ float sAmp[16 * 528];   // [w*4+q4][528] partials; reused as sXp
    __shared__ float sP[4 * 512];      // probs [h][j]

    const int tid  = threadIdx.x;
    const int i    = blockIdx.x;
    const int bB   = blockIdx.y;
    const int lane = tid & 63;
    const int w    = tid >> 6;
    const int l15  = lane & 15;
    const int q4   = lane >> 4;

    // ---- A-frags: G^T[o][d] = xi[d]*Wa[d][o], rows o = w*16+l15, in regs ----
    const float* xi = x + ((size_t)bB * N_ + i) * D_;
    const int oa = w * 16 + l15;
    short8 gh[4], gl[4];
    #pragma unroll
    for (int kc = 0; kc < 4; ++kc) {
        const int d0 = kc * 32 + q4 * 8;
        const f32x4 x0 = *(const f32x4*)&xi[d0];
        const f32x4 x1 = *(const f32x4*)&xi[d0 + 4];
        #pragma unroll
        for (int e = 0; e < 8; ++e) {
            const float xe = (e < 4) ? x0[e & 3] : x1[e & 3];
            const float g = xe * Wa[(d0 + e) * O_ + oa];
            ushort h, l; bf16split(g, h, l);
            gh[kc][e] = (short)h; gl[kc][e] = (short)l;
        }
    }

    // ---- epilogue constants (loop-invariant, in regs) ----
    const int oc = w * 16 + q4 * 4;
    const f32x4 aw0 = *(const f32x4*)&AW[(oc + 0) * H_];
    const f32x4 aw1 = *(const f32x4*)&AW[(oc + 1) * H_];
    const f32x4 aw2 = *(const f32x4*)&AW[(oc + 2) * H_];
    const f32x4 aw3 = *(const f32x4*)&AW[(oc + 3) * H_];
    const f32x4 b2 = { 2.f * ba[oc], 2.f * ba[oc + 1], 2.f * ba[oc + 2], 2.f * ba[oc + 3] };

    // ---- phase 1: 32 tiles, barrier-free, static double buffer ----
    const ushort* xfb = xf + (size_t)(bB * 32) * 8 * 512;
    short8 Bh0[4], Bl0[4], Bh1[4], Bl1[4];
    #pragma unroll
    for (int kc = 0; kc < 4; ++kc) {
        Bh0[kc] = *(const short8*)&xfb[(size_t)(kc * 2) * 512 + lane * 8];
        Bl0[kc] = *(const short8*)&xfb[(size_t)(kc * 2 + 1) * 512 + lane * 8];
    }

#define SCORE_STEP(BHc, BLc, BHn, BLn, JF)                                          \
    {                                                                               \
        if ((JF) < 31) {                                                            \
            const ushort* bp = xfb + (size_t)((JF) + 1) * 8 * 512;                  \
            BHn[0] = *(const short8*)&bp[0 * 512 + lane * 8];                       \
            BLn[0] = *(const short8*)&bp[1 * 512 + lane * 8];                       \
            BHn[1] = *(const short8*)&bp[2 * 512 + lane * 8];                       \
            BLn[1] = *(const short8*)&bp[3 * 512 + lane * 8];                       \
            BHn[2] = *(const short8*)&bp[4 * 512 + lane * 8];                       \
            BLn[2] = *(const short8*)&bp[5 * 512 + lane * 8];                       \
            BHn[3] = *(const short8*)&bp[6 * 512 + lane * 8];                       \
            BLn[3] = *(const short8*)&bp[7 * 512 + lane * 8];                       \
        }                                                                           \
        f32x4 acc = {0.f, 0.f, 0.f, 0.f};                                           \
        acc = __builtin_amdgcn_mfma_f32_16x16x32_bf16(gh[0], BHc[0], acc, 0, 0, 0); \
        acc = __builtin_amdgcn_mfma_f32_16x16x32_bf16(gl[0], BHc[0], acc, 0, 0, 0); \
        acc = __builtin_amdgcn_mfma_f32_16x16x32_bf16(gh[0], BLc[0], acc, 0, 0, 0); \
        acc = __builtin_amdgcn_mfma_f32_16x16x32_bf16(gh[1], BHc[1], acc, 0, 0, 0); \
        acc = __builtin_amdgcn_mfma_f32_16x16x32_bf16(gl[1], BHc[1], acc, 0, 0, 0); \
        acc = __builtin_amdgcn_mfma_f32_16x16x32_bf16(gh[1], BLc[1], acc, 0, 0, 0); \
        acc = __builtin_amdgcn_mfma_f32_16x16x32_bf16(gh[2], BHc[2], acc, 0, 0, 0); \
        acc = __builtin_amdgcn_mfma_f32_16x16x32_bf16(gl[2], BHc[2], acc, 0, 0, 0); \
        acc = __builtin_amdgcn_mfma_f32_16x16x32_bf16(gh[2], BLc[2], acc, 0, 0, 0); \
        acc = __builtin_amdgcn_mfma_f32_16x16x32_bf16(gh[3], BHc[3], acc, 0, 0, 0); \
        acc = __builtin_amdgcn_mfma_f32_16x16x32_bf16(gl[3], BHc[3], acc, 0, 0, 0); \
        acc = __builtin_amdgcn_mfma_f32_16x16x32_bf16(gh[3], BLc[3], acc, 0, 0, 0); \
        score_epilogue(acc, (JF), w, q4, l15, aw0, aw1, aw2, aw3, b2, sAmp);        \
    }

    for (int jt = 0; jt < 16; ++jt) {
        SCORE_STEP(Bh0, Bl0, Bh1, Bl1, 2 * jt)
        SCORE_STEP(Bh1, Bl1, Bh0, Bl0, 2 * jt + 1)
    }
#undef SCORE_STEP
    __syncthreads();

    // ---- phase 2: softmax over j (wave = head); combine 4 wave partials ----
    {
        const int h = w;
        float v[8];
        float m = -INFINITY;
        #pragma unroll
        for (int k = 0; k < 8; ++k) {
            const int j = k * 64 + lane;
            v[k] = sAmp[(0 * 4 + h) * 528 + j] + sAmp[(1 * 4 + h) * 528 + j]
                 + sAmp[(2 * 4 + h) * 528 + j] + sAmp[(3 * 4 + h) * 528 + j];
            m = fmaxf(m, v[k]);
        }
        #pragma unroll
        for (int s = 32; s >= 1; s >>= 1) m = fmaxf(m, __shfl_xor(m, s));
        float l = 0.f;
        #pragma unroll
        for (int k = 0; k < 8; ++k) { v[k] = __expf(v[k] - m); l += v[k]; }
        #pragma unroll
        for (int s = 32; s >= 1; s >>= 1) l += __shfl_xor(l, s);
        const float rinv = 1.f / l;
        #pragma unroll
        for (int k = 0; k < 8; ++k) sP[h * N_ + k * 64 + lane] = v[k] * rinv;
    }
    __syncthreads();

    // ---- phase 3: x1 = P.X via MFMA (A = P rows h, B = xfT K=j) ----
    f32x4 acc2[8];
    {
        const f32x4 z = {0.f, 0.f, 0.f, 0.f};
        #pragma unroll
        for (int nf = 0; nf < 8; ++nf) acc2[nf] = z;
    }
    #pragma unroll
    for (int c = 0; c < 4; ++c) {
        const int kc = w * 4 + c;
        const f32x4 p0 = *(const f32x4*)&sP[(l15 & 3) * 512 + kc * 32 + q4 * 8];
        const f32x4 p1 = *(const f32x4*)&sP[(l15 & 3) * 512 + kc * 32 + q4 * 8 + 4];
        float pv[8] = {p0[0], p0[1], p0[2], p0[3], p1[0], p1[1], p1[2], p1[3]};
        short8 pah, pal;
        #pragma unroll
        for (int e = 0; e < 8; ++e) {
            ushort h, l; bf16split(pv[e], h, l);
            pah[e] = (short)h; pal[e] = (short)l;
        }
        #pragma unroll
        for (int nf = 0; nf < 8; ++nf) {
            const size_t f2 = ((size_t)(bB * 16 + kc) * 8 + nf) * 2;
            const short8 xh = *(const short8*)&xfT[f2 * 512 + lane * 8];
            const short8 xl = *(const short8*)&xfT[(f2 + 1) * 512 + lane * 8];
            acc2[nf] = __builtin_amdgcn_mfma_f32_16x16x32_bf16(pah, xh, acc2[nf], 0, 0, 0);
            acc2[nf] = __builtin_amdgcn_mfma_f32_16x16x32_bf16(pal, xh, acc2[nf], 0, 0, 0);
            acc2[nf] = __builtin_amdgcn_mfma_f32_16x16x32_bf16(pah, xl, acc2[nf], 0, 0, 0);
        }
    }
    float* sXp = sAmp;   // reuse as [16][128] wave partials
    if (q4 == 0) {
        #pragma unroll
        for (int nf = 0; nf < 8; ++nf)
            #pragma unroll
            for (int r = 0; r < 4; ++r)
                sXp[(w * 4 + r) * 128 + nf * 16 + l15] = acc2[nf][r];
    }
    __syncthreads();

    // ---- phase 3b: reduce wave partials, split, store X1 ----
    {
        const int kap = tid * 2;
        const size_t row = (size_t)bB * N_ + i;
        float v0 = 0.f, v1 = 0.f;
        #pragma unroll
        for (int ww = 0; ww < 4; ++ww) {
            v0 += sXp[(ww * 4 + (kap >> 7)) * 128 + (kap & 127)];
            v1 += sXp[(ww * 4 + ((kap + 1) >> 7)) * 128 + ((kap + 1) & 127)];
        }
        ushort h0, l0, h1, l1;
        bf16split(v0, h0, l0);
        bf16split(v1, h1, l1);
        *(uint*)&X1h[row * 512 + kap] = (uint)h0 | ((uint)h1 << 16);
        *(uint*)&X1l[row * 512 + kap] = (uint)l0 | ((uint)l1 << 16);
    }
}

// ---------------------------------------------------------------------------
// proj_y_part: y = x1.PW' + x.NW + biases (MFMA) + per-block BN partial sums.
// ---------------------------------------------------------------------------
__global__ __launch_bounds__(256) void proj_y_part(
    const ushort* __restrict__ X1h, const ushort* __restrict__ X1l,
    const ushort* __restrict__ xf,
    const ushort* __restrict__ pwf, const ushort* __restrict__ nwf,
    const float* __restrict__ PWb, const float* __restrict__ NWb,
    float* __restrict__ y, float* __restrict__ part)
{
    const int tid = threadIdx.x, bid = blockIdx.x;
    const int lane = tid & 63, w = tid >> 6;
    const int l15 = lane & 15, q4 = lane >> 4;
    const int bi0 = bid * 16;
    const int b = bi0 >> 9, ig = (bi0 >> 4) & 31;

    f32x4 acc = {0.f, 0.f, 0.f, 0.f};
    #pragma unroll
    for (int kc = 0; kc < 16; ++kc) {
        const size_t arow = (size_t)(bi0 + l15) * 512 + kc * 32 + q4 * 8;
        const short8 ah = *(const short8*)&X1h[arow];
        const short8 al = *(const short8*)&X1l[arow];
        const int f3 = (kc * 4 + w) * 2;
        const short8 bhv = *(const short8*)&pwf[(size_t)f3 * 512 + lane * 8];
        const short8 blv = *(const short8*)&pwf[(size_t)(f3 + 1) * 512 + lane * 8];
        acc = __builtin_amdgcn_mfma_f32_16x16x32_bf16(ah, bhv, acc, 0, 0, 0);
        acc = __builtin_amdgcn_mfma_f32_16x16x32_bf16(al, bhv, acc, 0, 0, 0);
        acc = __builtin_amdgcn_mfma_f32_16x16x32_bf16(ah, blv, acc, 0, 0, 0);
    }
    #pragma unroll
    for (int kc = 0; kc < 4; ++kc) {
        const size_t fi = ((size_t)(b * 32 + ig) * 4 + kc) * 2;
        const short8 ah = *(const short8*)&xf[fi * 512 + lane * 8];
        const short8 al = *(const short8*)&xf[(fi + 1) * 512 + lane * 8];
        const int f4 = (kc * 4 + w) * 2;
        const short8 bhv = *(const short8*)&nwf[(size_t)f4 * 512 + lane * 8];
        const short8 blv = *(const short8*)&nwf[(size_t)(f4 + 1) * 512 + lane * 8];
        acc = __builtin_amdgcn_mfma_f32_16x16x32_bf16(ah, bhv, acc, 0, 0, 0);
        acc = __builtin_amdgcn_mfma_f32_16x16x32_bf16(al, bhv, acc, 0, 0, 0);
        acc = __builtin_amdgcn_mfma_f32_16x16x32_bf16(ah, blv, acc, 0, 0, 0);
    }
    const int oo = w * 16 + l15;
    const float bias = PWb[oo] + NWb[oo];
    float s = 0.f, sq = 0.f;
    #pragma unroll
    for (int r = 0; r < 4; ++r) {
        const float yv = acc[r] + bias;
        y[(size_t)(bi0 + q4 * 4 + r) * O_ + oo] = yv;
        s += yv; sq += yv * yv;
    }
    s  += __shfl_xor(s, 16);  s  += __shfl_xor(s, 32);
    sq += __shfl_xor(sq, 16); sq += __shfl_xor(sq, 32);
    if (q4 == 0) {
        part[bid * 256 + oo]       = s;
        part[bid * 256 + 128 + oo] = sq;
    }
}

__global__ __launch_bounds__(256) void bn_final(
    const float* __restrict__ part, const float* __restrict__ gamma,
    const float* __restrict__ beta, float* __restrict__ stats)
{
    const int tid = threadIdx.x, o = tid & 63, g = tid >> 6;
    float s = 0.f, sq = 0.f;
    #pragma unroll 4
    for (int k = 0; k < 32; ++k) {
        const int blk = g * 32 + k;
        s  += part[blk * 256 + o];
        sq += part[blk * 256 + 128 + o];
    }
    __shared__ float ls[4][64], lq[4][64];
    ls[g][o] = s; lq[g][o] = sq;
    __syncthreads();
    if (tid < 64) {
        const float inv = 1.f / 2048.f;
        const float ts = ls[0][tid] + ls[1][tid] + ls[2][tid] + ls[3][tid];
        const float tq = lq[0][tid] + lq[1][tid] + lq[2][tid] + lq[3][tid];
        const float mu  = ts * inv;
        const float var = tq * inv - mu * mu;
        const float rstd = rsqrtf(var + 1e-5f);
        const float sc = gamma[tid] * rstd;
        stats[tid]      = sc;
        stats[64 + tid] = beta[tid] - mu * sc;
    }
}

__global__ __launch_bounds__(256) void bn_apply(
    float* __restrict__ y, const float* __restrict__ stats)
{
    const int idx = blockIdx.x * 256 + threadIdx.x;
    f32x4 v = *(f32x4*)&y[idx * 4];
    const int o0 = (idx * 4) & 63;
    #pragma unroll
    for (int k = 0; k < 4; ++k) {
        const float t = v[k] * stats[o0 + k] + stats[64 + o0 + k];
        v[k] = t > 0.f ? SELU_SCALE * t : SELU_SCALE_ALPHA * (__expf(t) - 1.f);
    }
    *(f32x4*)&y[idx * 4] = v;
}

extern "C" void kernel_launch(void* const* d_in, const int* in_sizes, int n_in,
                              void* d_out, int out_size, void* d_ws, size_t ws_size,
                              hipStream_t stream)
{
    (void)in_sizes; (void)n_in; (void)out_size; (void)ws_size;
    const float* x     = (const float*)d_in[0];
    const float* Wa    = (const float*)d_in[1];
    const float* ba    = (const float*)d_in[2];
    const float* AW    = (const float*)d_in[3];
    const float* PW    = (const float*)d_in[4];
    const float* PWb   = (const float*)d_in[5];
    const float* NW    = (const float*)d_in[6];
    const float* NWb   = (const float*)d_in[7];
    const float* gamma = (const float*)d_in[8];
    const float* beta  = (const float*)d_in[9];

    char* ws = (char*)d_ws;
    ushort* xf    = (ushort*)ws;                                   // 1 MB
    ushort* xfT   = (ushort*)(ws + (1 << 20));                     // 1 MB
    ushort* X1h   = (ushort*)(ws + (2 << 20));                     // 2 MB
    ushort* X1l   = (ushort*)(ws + (4 << 20));                     // 2 MB
    ushort* pwf   = (ushort*)(ws + (6 << 20));                     // 128 KB
    ushort* nwf   = (ushort*)(ws + (6 << 20) + (128 << 10));       // 32 KB
    float*  part  = (float*)(ws + (6 << 20) + (160 << 10));        // 128 KB
    float*  stats = (float*)(ws + (6 << 20) + (288 << 10));        // 512 B
    float*  y     = (float*)d_out;

    prep_frags<<<276, 256, 0, stream>>>(x, PW, NW, xf, xfT, pwf, nwf);
    attn_scores<<<dim3(N_, B_), 256, 0, stream>>>(x, xf, xfT, Wa, ba, AW, X1h, X1l);
    proj_y_part<<<128, 256, 0, stream>>>(X1h, X1l, xf, pwf, nwf, PWb, NWb, y, part);
    bn_final<<<1, 256, 0, stream>>>(part, gamma, beta, stats);
    bn_apply<<<128, 256, 0, stream>>>(y, stats);
}